// Round 3
// baseline (254.840 us; speedup 1.0000x reference)
//
#include <hip/hip_runtime.h>

// Dense 2D spatial transformer (bilinear warp, dense flow), 4096x4096 f32.
//
// Round 7: interior specialization. R6 post-mortem: LDS staging removed the
// TA-gather bottleneck but only netted 67->62.8us. Revised model: ~28us of
// the kernel is VALU (85 ops/px of border-exact clamp/predicate/selector
// math -- consistent with R4's measured VALUBusy 34% x 78.6us = 26.7us),
// overlapped imperfectly with a ~35us L3/HBM stream floor.
//
// Fix: border math is only REACHABLE for pixels within HALO of the image
// edge. For interior blocks (~93%), once the in-window predicate `ok` holds,
// every clamp is provably inactive, all 4 taps are in-image, and the pair
// selectors are (0,1): per-pixel work collapses to floor + dH/dW + 4 weights
// + 1 mad (~30 VALU). The never-taken-in-practice (max|flow|~5.5 < HALO=8)
// !ok fallback recomputes the FULL reference math with global pair-gathers,
// preserving exactness. Border-ring blocks (block-uniform branch) run the
// full-exact R5-style global-gather path and skip staging entirely.
//
// Reference math (full path, verbatim from passing R5/R6):
//   H_up=(flow_h+h)+1 ; W_up=(flow_w+w)+1 ; hf=floor, hc=hf+1, clamp to
//   [0,H+1] (padded dims); dH=(float)hc_clamped-H_up (clamp BEFORE weights);
//   out = v00*(dW*dH)+v01*((1-dW)*dH)+v10*(dW*(1-dH))+v11*((1-dW)*(1-dH));
//   taps outside the image contribute 0 via zeroed weights; row taps paired
//   as float2 from base cb=clamp(cf,0,W-2) with {0,1} selectors folded into
//   the weights. Interior fast path == this expression with clamps inactive.

#define IMG_H 4096
#define IMG_W 4096
#define TR 16                 // output rows per block
#define TC 128                // output cols per block
#define HALO 8
#define SR (TR + 2 * HALO)    // 32 staged rows
#define SC (TC + 2 * HALO)    // 144 staged cols
#define SC4 (SC / 4)          // 36 float4 per staged row
#define NCHUNK (SR * SC4)     // 1152 float4 stage chunks

typedef float f2  __attribute__((ext_vector_type(2)));              // 8B-aligned
typedef float f2u __attribute__((ext_vector_type(2), aligned(4)));  // 4B-aligned pair
typedef float f4  __attribute__((ext_vector_type(4)));

// Full-exact per-pixel path (reference math + global paired gathers).
// Used by border blocks for every pixel and by interior lanes that fail
// the in-window check (P ~ 0 for N(0,1) flow, required for exactness).
__device__ __forceinline__ float full_pixel(const float* __restrict__ img,
                                            float fhv, float fwv, int h, int w)
{
    float Hu = (fhv + (float)h) + 1.0f;   // exact reference grouping
    float Wu = (fwv + (float)w) + 1.0f;

    int hf = (int)floorf(Hu);
    int wf = (int)floorf(Wu);
    int hc = hf + 1;
    int wc = wf + 1;

    int hfc = min(max(hf, 0), IMG_H + 1);
    int hcc = min(max(hc, 0), IMG_H + 1);
    int wfc = min(max(wf, 0), IMG_W + 1);
    int wcc = min(max(wc, 0), IMG_W + 1);

    float dH = (float)hcc - Hu;
    float dW = (float)wcc - Wu;

    int rf = hfc - 1, rc = hcc - 1, cf = wfc - 1, cc = wcc - 1;
    bool rf_in = (unsigned)rf < IMG_H;
    bool rc_in = (unsigned)rc < IMG_H;
    bool cf_in = (unsigned)cf < IMG_W;
    bool cc_in = (unsigned)cc < IMG_W;

    int rf_cl = min(max(rf, 0), IMG_H - 1);
    int rc_cl = min(max(rc, 0), IMG_H - 1);
    int cf_cl = min(max(cf, 0), IMG_W - 1);
    int cc_cl = min(max(cc, 0), IMG_W - 1);
    int cb    = min(max(cf, 0), IMG_W - 2);   // float2 pair base

    int sf = cf_cl - cb;   // 0 or 1
    int sc = cc_cl - cb;   // 0 or 1

    float A = dW * dH;
    float B = dW * (1.0f - dH);
    float C = (1.0f - dW) * dH;
    float D = (1.0f - dW) * (1.0f - dH);
    float w00 = (rf_in && cf_in) ? A : 0.0f;
    float w10 = (rc_in && cf_in) ? B : 0.0f;
    float w01 = (rf_in && cc_in) ? C : 0.0f;
    float w11 = (rc_in && cc_in) ? D : 0.0f;

    float a0x = (sf ? 0.0f : w00) + (sc ? 0.0f : w01);
    float a0y = (sf ? w00 : 0.0f) + (sc ? w01 : 0.0f);
    float a1x = (sf ? 0.0f : w10) + (sc ? 0.0f : w11);
    float a1y = (sf ? w10 : 0.0f) + (sc ? w11 : 0.0f);

    f2u p0 = *(const f2u*)(img + (rf_cl << 12) + cb);
    f2u p1 = *(const f2u*)(img + (rc_cl << 12) + cb);
    return p0.x * a0x + p0.y * a0y + p1.x * a1x + p1.y * a1y;
}

__global__ __launch_bounds__(256) void warp_bilinear_kernel(
    const float* __restrict__ img,   // [H, W]
    const float* __restrict__ flow,  // [2, H, W]
    float* __restrict__ out)         // [H, W]
{
    __shared__ float tile[SR * SC];  // 18432 B

    const int HW   = IMG_H * IMG_W;
    const int tid  = threadIdx.x;
    const int lane = tid & 63;
    const int wv   = tid >> 6;                      // 0..3
    const int bx   = blockIdx.x, by = blockIdx.y;
    const int w0   = bx * TC + lane * 2;            // 2 cols/thread (even)
    const int h0   = by * TR + wv * 4;              // 4 rows/thread
    const int r_lo = by * TR - HALO;                // staged window origin
    const int c_lo = bx * TC - HALO;

    const bool border = (bx == 0) | (bx == gridDim.x - 1) |
                        (by == 0) | (by == gridDim.y - 1);

    // ---- flow loads first (streaming, needed right after the barrier) ----
    int rowidx[4];
    f2  fh[4], fw[4];
    #pragma unroll
    for (int r = 0; r < 4; ++r)
        rowidx[r] = (h0 + r) * IMG_W + w0;
    #pragma unroll
    for (int r = 0; r < 4; ++r)
        fh[r] = __builtin_nontemporal_load((const f2*)(flow + rowidx[r]));
    #pragma unroll
    for (int r = 0; r < 4; ++r)
        fw[r] = __builtin_nontemporal_load((const f2*)(flow + HW + rowidx[r]));

    // ---- stage image window into LDS (interior blocks only) ----
    if (!border) {
        #pragma unroll
        for (int it = 0; it < 5; ++it) {
            int t = tid + it * 256;
            if (t < NCHUNK) {
                int i  = t / SC4;                    // staged row 0..31
                int m  = t - i * SC4;                // f4 chunk 0..35
                // interior windows are fully in-image; clamp kept (cheap, safe)
                int gr = min(max(r_lo + i, 0), IMG_H - 1);
                int gc = min(max(c_lo + 4 * m, 0), IMG_W - 4);
                f4 v = *(const f4*)(img + gr * IMG_W + gc);
                *(f4*)(tile + i * SC + 4 * m) = v;
            }
        }
    }
    __syncthreads();   // block-uniform: all threads reach this

    // ---- border-ring blocks: full-exact global-gather path ----
    if (border) {
        #pragma unroll
        for (int r = 0; r < 4; ++r) {
            f2 res;
            #pragma unroll
            for (int c = 0; c < 2; ++c)
                res[c] = full_pixel(img, fh[r][c], fw[r][c], h0 + r, w0 + c);
            __builtin_nontemporal_store(res, (f2*)(out + rowidx[r]));
        }
        return;
    }

    // ---- interior fast path: clamps provably inactive once in-window ----
    // (interior block => window rows [r_lo, r_lo+SR-1] in [8,4087], cols in
    //  [120,3975]; ok => rf,rc,cf,cc all strictly in-image, cb==cf, sf=0,sc=1)
    int   li0[4][2], li1[4][2];
    float A_[4][2], B_[4][2], C_[4][2], D_[4][2];
    bool  ok = true;
    const int rbase = -1 - r_lo;   // i0 = hf + rbase
    const int cbase = -1 - c_lo;   // jb = wf + cbase

    #pragma unroll
    for (int r = 0; r < 4; ++r) {
        #pragma unroll
        for (int c = 0; c < 2; ++c) {
            // exact reference grouping: (flow + mesh) + 1.0
            float Hu = (fh[r][c] + (float)(h0 + r)) + 1.0f;
            float Wu = (fw[r][c] + (float)(w0 + c)) + 1.0f;

            int hf = (int)floorf(Hu);
            int wf = (int)floorf(Wu);
            float dH = (float)(hf + 1) - Hu;
            float dW = (float)(wf + 1) - Wu;

            int i0 = hf + rbase;           // window row of top tap
            int jb = wf + cbase;           // window col of pair base
            ok = ok && ((unsigned)i0 < SR - 1) && ((unsigned)jb < SC - 1);
            li0[r][c] = i0 * SC + jb;
            li1[r][c] = li0[r][c] + SC;

            float omH = 1.0f - dH, omW = 1.0f - dW;
            A_[r][c] = dW * dH;            // weight of (rf,cf) = pair0.x
            C_[r][c] = omW * dH;           // weight of (rf,cc) = pair0.y
            B_[r][c] = dW * omH;           // weight of (rc,cf) = pair1.x
            D_[r][c] = omW * omH;          // weight of (rc,cc) = pair1.y
        }
    }

    float res[4][2];
    if (__builtin_expect(ok, 1)) {
        // batched LDS pair gathers (16 x ds_read2_b32), then blend
        float q0x[4][2], q0y[4][2], q1x[4][2], q1y[4][2];
        #pragma unroll
        for (int r = 0; r < 4; ++r)
            #pragma unroll
            for (int c = 0; c < 2; ++c) {
                q0x[r][c] = tile[li0[r][c]];
                q0y[r][c] = tile[li0[r][c] + 1];
                q1x[r][c] = tile[li1[r][c]];
                q1y[r][c] = tile[li1[r][c] + 1];
            }
        #pragma unroll
        for (int r = 0; r < 4; ++r)
            #pragma unroll
            for (int c = 0; c < 2; ++c)
                res[r][c] = q0x[r][c] * A_[r][c] + q0y[r][c] * C_[r][c]
                          + q1x[r][c] * B_[r][c] + q1y[r][c] * D_[r][c];
    }
    if (__builtin_expect(!ok, 0)) {
        // tap escaped the staged window: full-exact recompute (rare/never)
        #pragma unroll
        for (int r = 0; r < 4; ++r)
            #pragma unroll
            for (int c = 0; c < 2; ++c)
                res[r][c] = full_pixel(img, fh[r][c], fw[r][c],
                                       h0 + r, w0 + c);
    }

    #pragma unroll
    for (int r = 0; r < 4; ++r) {
        f2 v; v[0] = res[r][0]; v[1] = res[r][1];
        __builtin_nontemporal_store(v, (f2*)(out + rowidx[r]));
    }
}

extern "C" void kernel_launch(void* const* d_in, const int* in_sizes, int n_in,
                              void* d_out, int out_size, void* d_ws, size_t ws_size,
                              hipStream_t stream) {
    const float* img  = (const float*)d_in[0];   // [1,1,4096,4096]
    const float* flow = (const float*)d_in[1];   // [1,2,4096,4096]
    float* out = (float*)d_out;                  // [1,1,4096,4096]

    dim3 grid(IMG_W / TC, IMG_H / TR);           // (32, 256)
    dim3 block(256);
    warp_bilinear_kernel<<<grid, block, 0, stream>>>(img, flow, out);
}